// Round 1
// baseline (769.835 us; speedup 1.0000x reference)
//
#include <hip/hip_runtime.h>

#define N_NODES 50000
#define N_EDGES 800000
#define IN_C    128
#define HID_C   128
#define OUT_C   64

// ---------------------------------------------------------------------------
// Layer-1 dual matmul: p1 = x @ W1l   (no bias; bias added post-aggregation)
//                      t1 = x @ W1r
// Block: 128 threads (one per output channel), 8 nodes per block.
// x rows staged in LDS, read back as float4 broadcasts.
// ---------------------------------------------------------------------------
__global__ __launch_bounds__(128) void mm1_kernel(
    const float* __restrict__ x, const float* __restrict__ Wl,
    const float* __restrict__ Wr, float* __restrict__ p1,
    float* __restrict__ t1)
{
    __shared__ float xs[8][IN_C];
    const int j = threadIdx.x;
    const int base = blockIdx.x * 8;

#pragma unroll
    for (int n = 0; n < 8; ++n) {
        const int node = base + n;
        xs[n][j] = (node < N_NODES) ? x[node * IN_C + j] : 0.0f;
    }
    __syncthreads();

    float accl[8], accr[8];
#pragma unroll
    for (int n = 0; n < 8; ++n) { accl[n] = 0.0f; accr[n] = 0.0f; }

    for (int k = 0; k < IN_C; k += 4) {
        float wl[4], wr[4];
#pragma unroll
        for (int q = 0; q < 4; ++q) {
            wl[q] = Wl[(k + q) * HID_C + j];
            wr[q] = Wr[(k + q) * HID_C + j];
        }
#pragma unroll
        for (int n = 0; n < 8; ++n) {
            const float4 xv = *reinterpret_cast<const float4*>(&xs[n][k]);
            accl[n] = fmaf(xv.x, wl[0], accl[n]);
            accl[n] = fmaf(xv.y, wl[1], accl[n]);
            accl[n] = fmaf(xv.z, wl[2], accl[n]);
            accl[n] = fmaf(xv.w, wl[3], accl[n]);
            accr[n] = fmaf(xv.x, wr[0], accr[n]);
            accr[n] = fmaf(xv.y, wr[1], accr[n]);
            accr[n] = fmaf(xv.z, wr[2], accr[n]);
            accr[n] = fmaf(xv.w, wr[3], accr[n]);
        }
    }

#pragma unroll
    for (int n = 0; n < 8; ++n) {
        const int node = base + n;
        if (node < N_NODES) {
            p1[node * HID_C + j] = accl[n];
            t1[node * HID_C + j] = accr[n];
        }
    }
}

// ---------------------------------------------------------------------------
// Edge-parallel scatter-add, layer 1 (128 channels) + degree count.
// One thread per (edge, channel).
// ---------------------------------------------------------------------------
__global__ __launch_bounds__(256) void scatter1_kernel(
    const float* __restrict__ p1, const int* __restrict__ src,
    const int* __restrict__ dst, float* agg, float* deg)
{
    const int i = blockIdx.x * blockDim.x + threadIdx.x;   // < N_EDGES*128
    const int e = i >> 7;
    const int c = i & 127;
    const int s = src[e];
    const int d = dst[e];
    if ((unsigned)s < N_NODES && (unsigned)d < N_NODES) {
        unsafeAtomicAdd(&agg[d * HID_C + c], p1[s * HID_C + c]);
        if (c == 0) unsafeAtomicAdd(&deg[d], 1.0f);
    }
}

// ---------------------------------------------------------------------------
// finish1: h = relu(agg/max(deg,1) + b1 + t1), written in-place into agg.
// ---------------------------------------------------------------------------
__global__ __launch_bounds__(256) void finish1_kernel(
    float* agg, const float* __restrict__ t1, const float* __restrict__ b1,
    const float* __restrict__ deg)
{
    const int i = blockIdx.x * blockDim.x + threadIdx.x;   // < N_NODES*128
    if (i < N_NODES * HID_C) {
        const int node = i >> 7;
        const int c = i & 127;
        const float inv = 1.0f / fmaxf(deg[node], 1.0f);
        const float v = agg[i] * inv + b1[c] + t1[i];
        agg[i] = fmaxf(v, 0.0f);
    }
}

// ---------------------------------------------------------------------------
// Layer-2 dual matmul: p2 = h @ W2l, t2 = h @ W2r  (128 -> 64 each).
// Block: 128 threads; lanes 0..63 (wave 0) do W2l, lanes 64..127 (wave 1) W2r.
// ---------------------------------------------------------------------------
__global__ __launch_bounds__(128) void mm2_kernel(
    const float* __restrict__ h, const float* __restrict__ Wl,
    const float* __restrict__ Wr, float* __restrict__ p2,
    float* __restrict__ t2)
{
    __shared__ float hs[8][HID_C];
    const int j = threadIdx.x;
    const int base = blockIdx.x * 8;

#pragma unroll
    for (int n = 0; n < 8; ++n) {
        const int node = base + n;
        hs[n][j] = (node < N_NODES) ? h[node * HID_C + j] : 0.0f;
    }
    __syncthreads();

    const bool left = (j < 64);
    const float* __restrict__ W = left ? Wl : Wr;
    const int col = j & 63;

    float acc[8];
#pragma unroll
    for (int n = 0; n < 8; ++n) acc[n] = 0.0f;

    for (int k = 0; k < HID_C; k += 4) {
        float w[4];
#pragma unroll
        for (int q = 0; q < 4; ++q) w[q] = W[(k + q) * OUT_C + col];
#pragma unroll
        for (int n = 0; n < 8; ++n) {
            const float4 hv = *reinterpret_cast<const float4*>(&hs[n][k]);
            acc[n] = fmaf(hv.x, w[0], acc[n]);
            acc[n] = fmaf(hv.y, w[1], acc[n]);
            acc[n] = fmaf(hv.z, w[2], acc[n]);
            acc[n] = fmaf(hv.w, w[3], acc[n]);
        }
    }

    float* outp = left ? p2 : t2;
#pragma unroll
    for (int n = 0; n < 8; ++n) {
        const int node = base + n;
        if (node < N_NODES) outp[node * OUT_C + col] = acc[n];
    }
}

// ---------------------------------------------------------------------------
// Edge-parallel scatter-add, layer 2 (64 channels; deg already computed).
// ---------------------------------------------------------------------------
__global__ __launch_bounds__(256) void scatter2_kernel(
    const float* __restrict__ p2, const int* __restrict__ src,
    const int* __restrict__ dst, float* agg)
{
    const int i = blockIdx.x * blockDim.x + threadIdx.x;   // < N_EDGES*64
    const int e = i >> 6;
    const int c = i & 63;
    const int s = src[e];
    const int d = dst[e];
    if ((unsigned)s < N_NODES && (unsigned)d < N_NODES) {
        unsafeAtomicAdd(&agg[d * OUT_C + c], p2[s * OUT_C + c]);
    }
}

// ---------------------------------------------------------------------------
// finish2: out = agg/max(deg,1) + b2 + t2
// ---------------------------------------------------------------------------
__global__ __launch_bounds__(256) void finish2_kernel(
    const float* __restrict__ agg, const float* __restrict__ t2,
    const float* __restrict__ b2, const float* __restrict__ deg,
    float* __restrict__ out)
{
    const int i = blockIdx.x * blockDim.x + threadIdx.x;   // < N_NODES*64
    if (i < N_NODES * OUT_C) {
        const int node = i >> 6;
        const int c = i & 63;
        const float inv = 1.0f / fmaxf(deg[node], 1.0f);
        out[i] = fmaf(agg[i], inv, b2[c] + t2[i]);
    }
}

extern "C" void kernel_launch(void* const* d_in, const int* in_sizes, int n_in,
                              void* d_out, int out_size, void* d_ws, size_t ws_size,
                              hipStream_t stream)
{
    const float* x   = (const float*)d_in[0];
    const int*   ei  = (const int*)d_in[1];      // int32 (JAX canonicalizes int64)
    const float* W1l = (const float*)d_in[2];
    const float* b1  = (const float*)d_in[3];
    const float* W1r = (const float*)d_in[4];
    const float* W2l = (const float*)d_in[5];
    const float* b2  = (const float*)d_in[6];
    const float* W2r = (const float*)d_in[7];
    float* out = (float*)d_out;

    const int* src = ei;
    const int* dst = ei + N_EDGES;

    // Workspace layout (floats)
    float* ws = (float*)d_ws;
    const size_t NH = (size_t)N_NODES * HID_C;   // 6.4M
    const size_t NO = (size_t)N_NODES * OUT_C;   // 3.2M
    float* p1   = ws;                 // [NH]
    float* t1   = ws + NH;            // [NH]
    float* agg1 = ws + 2 * NH;        // [NH]  (becomes h in-place)
    float* deg  = ws + 3 * NH;        // [N_NODES]
    // layer-2 reuse of dead regions:
    float* p2   = t1;                 // [NO]
    float* t2   = t1 + NO;            // [NO]
    float* agg2 = p1;                 // [NO]

    const size_t need = (3 * NH + N_NODES) * sizeof(float);
    if (ws_size < need) return;  // workspace too small; cannot proceed

    // Zero agg1 + deg (ws is poisoned 0xAA before every call)
    hipMemsetAsync(agg1, 0, NH * sizeof(float), stream);
    hipMemsetAsync(deg, 0, N_NODES * sizeof(float), stream);

    // Layer 1
    mm1_kernel<<<(N_NODES + 7) / 8, 128, 0, stream>>>(x, W1l, W1r, p1, t1);
    scatter1_kernel<<<(N_EDGES * 128) / 256, 256, 0, stream>>>(p1, src, dst, agg1, deg);
    finish1_kernel<<<(N_NODES * HID_C + 255) / 256, 256, 0, stream>>>(agg1, t1, b1, deg);
    float* h = agg1;

    // Layer 2 (pre-transform before aggregating: agg(h)@W == agg(h@W))
    mm2_kernel<<<(N_NODES + 7) / 8, 128, 0, stream>>>(h, W2l, W2r, p2, t2);
    hipMemsetAsync(agg2, 0, NO * sizeof(float), stream);
    scatter2_kernel<<<(N_EDGES * 64) / 256, 256, 0, stream>>>(p2, src, dst, agg2);
    finish2_kernel<<<(N_NODES * OUT_C + 255) / 256, 256, 0, stream>>>(agg2, t2, b2, deg, out);
}

// Round 2
// 363.964 us; speedup vs baseline: 2.1151x; 2.1151x over previous
//
#include <hip/hip_runtime.h>

#define N_NODES 50000
#define N_EDGES 800000
#define IN_C    128
#define HID_C   128
#define OUT_C   64
#define NBLK    ((N_NODES + 255) / 256)   // 196 scan blocks

// ---------------------------------------------------------------------------
// Layer-1 dual matmul: p1 = x @ W1l (bias deferred), t1 = x @ W1r
// 128 threads (one per output channel), 8 nodes per block, x rows in LDS.
// ---------------------------------------------------------------------------
__global__ __launch_bounds__(128) void mm1_kernel(
    const float* __restrict__ x, const float* __restrict__ Wl,
    const float* __restrict__ Wr, float* __restrict__ p1,
    float* __restrict__ t1)
{
    __shared__ float xs[8][IN_C];
    const int j = threadIdx.x;
    const int base = blockIdx.x * 8;

#pragma unroll
    for (int n = 0; n < 8; ++n) {
        const int node = base + n;
        xs[n][j] = (node < N_NODES) ? x[node * IN_C + j] : 0.0f;
    }
    __syncthreads();

    float accl[8], accr[8];
#pragma unroll
    for (int n = 0; n < 8; ++n) { accl[n] = 0.0f; accr[n] = 0.0f; }

    for (int k = 0; k < IN_C; k += 4) {
        float wl[4], wr[4];
#pragma unroll
        for (int q = 0; q < 4; ++q) {
            wl[q] = Wl[(k + q) * HID_C + j];
            wr[q] = Wr[(k + q) * HID_C + j];
        }
#pragma unroll
        for (int n = 0; n < 8; ++n) {
            const float4 xv = *reinterpret_cast<const float4*>(&xs[n][k]);
            accl[n] = fmaf(xv.x, wl[0], accl[n]);
            accl[n] = fmaf(xv.y, wl[1], accl[n]);
            accl[n] = fmaf(xv.z, wl[2], accl[n]);
            accl[n] = fmaf(xv.w, wl[3], accl[n]);
            accr[n] = fmaf(xv.x, wr[0], accr[n]);
            accr[n] = fmaf(xv.y, wr[1], accr[n]);
            accr[n] = fmaf(xv.z, wr[2], accr[n]);
            accr[n] = fmaf(xv.w, wr[3], accr[n]);
        }
    }

#pragma unroll
    for (int n = 0; n < 8; ++n) {
        const int node = base + n;
        if (node < N_NODES) {
            p1[node * HID_C + j] = accl[n];
            t1[node * HID_C + j] = accr[n];
        }
    }
}

// ---------------------------------------------------------------------------
// CSR build: histogram of dst, exclusive scan, edge fill.
// ---------------------------------------------------------------------------
__global__ __launch_bounds__(256) void hist_kernel(
    const int* __restrict__ dst, int* cnt)
{
    const int e = blockIdx.x * 256 + threadIdx.x;
    if (e < N_EDGES) atomicAdd(&cnt[dst[e]], 1);
}

__global__ __launch_bounds__(256) void scan_reduce_kernel(
    const int* __restrict__ cnt, int* __restrict__ bsums)
{
    __shared__ int s[256];
    const int t = threadIdx.x;
    const int i = blockIdx.x * 256 + t;
    s[t] = (i < N_NODES) ? cnt[i] : 0;
    __syncthreads();
    for (int off = 128; off > 0; off >>= 1) {
        if (t < off) s[t] += s[t + off];
        __syncthreads();
    }
    if (t == 0) bsums[blockIdx.x] = s[0];
}

__global__ __launch_bounds__(256) void scan_bsums_kernel(int* bsums)
{
    __shared__ int s[256];
    const int t = threadIdx.x;
    const int v = (t < NBLK) ? bsums[t] : 0;
    s[t] = v;
    __syncthreads();
    for (int off = 1; off < 256; off <<= 1) {
        const int add = (t >= off) ? s[t - off] : 0;
        __syncthreads();
        s[t] += add;
        __syncthreads();
    }
    if (t < NBLK) bsums[t] = s[t] - v;   // exclusive
}

__global__ __launch_bounds__(256) void scan_final_kernel(
    const int* __restrict__ cnt, const int* __restrict__ bsums,
    int* __restrict__ row_ptr)
{
    __shared__ int s[256];
    const int t = threadIdx.x;
    const int i = blockIdx.x * 256 + t;
    const int v = (i < N_NODES) ? cnt[i] : 0;
    s[t] = v;
    __syncthreads();
    for (int off = 1; off < 256; off <<= 1) {
        const int add = (t >= off) ? s[t - off] : 0;
        __syncthreads();
        s[t] += add;
        __syncthreads();
    }
    if (i < N_NODES) row_ptr[i] = s[t] - v + bsums[blockIdx.x];
}

__global__ __launch_bounds__(256) void fill_kernel(
    const int* __restrict__ src, const int* __restrict__ dst,
    const int* __restrict__ row_ptr, int* fillc, int* __restrict__ csr)
{
    const int e = blockIdx.x * 256 + threadIdx.x;
    if (e < N_EDGES) {
        const int d = dst[e];
        const int pos = atomicAdd(&fillc[d], 1);
        csr[row_ptr[d] + pos] = src[e];
    }
}

// ---------------------------------------------------------------------------
// agg1: one block per node, 128 threads (one per channel).
// h[i] = relu( mean_{s in N(i)} p1[s] + b1 + t1[i] ), h written IN PLACE of t1.
// ---------------------------------------------------------------------------
__global__ __launch_bounds__(128) void agg1_kernel(
    const float* __restrict__ p1, float* h /* aliases t1 */,
    const float* __restrict__ b1, const int* __restrict__ row_ptr,
    const int* __restrict__ cnt, const int* __restrict__ csr)
{
    __shared__ int sh[128];
    const int node = blockIdx.x;
    const int c = threadIdx.x;
    const int start = row_ptr[node];
    const int degi = cnt[node];

    float acc = 0.0f;
    for (int base = 0; base < degi; base += 128) {
        const int m = min(128, degi - base);
        if (c < m) sh[c] = csr[start + base + c];
        __syncthreads();
        for (int k = 0; k < m; ++k)
            acc += p1[sh[k] * HID_C + c];
        __syncthreads();
    }
    const float inv = 1.0f / fmaxf((float)degi, 1.0f);
    const int i = node * HID_C + c;
    h[i] = fmaxf(fmaf(acc, inv, b1[c] + h[i]), 0.0f);
}

// ---------------------------------------------------------------------------
// Layer-2 dual matmul: p2 = h @ W2l, t2 = h @ W2r  (128 -> 64 each).
// ---------------------------------------------------------------------------
__global__ __launch_bounds__(128) void mm2_kernel(
    const float* __restrict__ h, const float* __restrict__ Wl,
    const float* __restrict__ Wr, float* __restrict__ p2,
    float* __restrict__ t2)
{
    __shared__ float hs[8][HID_C];
    const int j = threadIdx.x;
    const int base = blockIdx.x * 8;

#pragma unroll
    for (int n = 0; n < 8; ++n) {
        const int node = base + n;
        hs[n][j] = (node < N_NODES) ? h[node * HID_C + j] : 0.0f;
    }
    __syncthreads();

    const bool left = (j < 64);
    const float* __restrict__ W = left ? Wl : Wr;
    const int col = j & 63;

    float acc[8];
#pragma unroll
    for (int n = 0; n < 8; ++n) acc[n] = 0.0f;

    for (int k = 0; k < HID_C; k += 4) {
        float w[4];
#pragma unroll
        for (int q = 0; q < 4; ++q) w[q] = W[(k + q) * OUT_C + col];
#pragma unroll
        for (int n = 0; n < 8; ++n) {
            const float4 hv = *reinterpret_cast<const float4*>(&hs[n][k]);
            acc[n] = fmaf(hv.x, w[0], acc[n]);
            acc[n] = fmaf(hv.y, w[1], acc[n]);
            acc[n] = fmaf(hv.z, w[2], acc[n]);
            acc[n] = fmaf(hv.w, w[3], acc[n]);
        }
    }

    float* outp = left ? p2 : t2;
#pragma unroll
    for (int n = 0; n < 8; ++n) {
        const int node = base + n;
        if (node < N_NODES) outp[node * OUT_C + col] = acc[n];
    }
}

// ---------------------------------------------------------------------------
// agg2: one block per node, 64 threads. out = mean(p2[src]) + b2 + t2.
// ---------------------------------------------------------------------------
__global__ __launch_bounds__(64) void agg2_kernel(
    const float* __restrict__ p2, const float* __restrict__ t2,
    const float* __restrict__ b2, const int* __restrict__ row_ptr,
    const int* __restrict__ cnt, const int* __restrict__ csr,
    float* __restrict__ out)
{
    __shared__ int sh[64];
    const int node = blockIdx.x;
    const int c = threadIdx.x;
    const int start = row_ptr[node];
    const int degi = cnt[node];

    float acc = 0.0f;
    for (int base = 0; base < degi; base += 64) {
        const int m = min(64, degi - base);
        if (c < m) sh[c] = csr[start + base + c];
        __syncthreads();
        for (int k = 0; k < m; ++k)
            acc += p2[sh[k] * OUT_C + c];
        __syncthreads();
    }
    const float inv = 1.0f / fmaxf((float)degi, 1.0f);
    const int i = node * OUT_C + c;
    out[i] = fmaf(acc, inv, b2[c] + t2[i]);
}

extern "C" void kernel_launch(void* const* d_in, const int* in_sizes, int n_in,
                              void* d_out, int out_size, void* d_ws, size_t ws_size,
                              hipStream_t stream)
{
    const float* x   = (const float*)d_in[0];
    const int*   ei  = (const int*)d_in[1];
    const float* W1l = (const float*)d_in[2];
    const float* b1  = (const float*)d_in[3];
    const float* W1r = (const float*)d_in[4];
    const float* W2l = (const float*)d_in[5];
    const float* b2  = (const float*)d_in[6];
    const float* W2r = (const float*)d_in[7];
    float* out = (float*)d_out;

    const int* src = ei;
    const int* dst = ei + N_EDGES;

    const size_t NH = (size_t)N_NODES * HID_C;   // 6.4M floats
    const size_t NO = (size_t)N_NODES * OUT_C;   // 3.2M floats

    // Workspace layout
    float* ws = (float*)d_ws;
    float* p1 = ws;            // [NH]  layer-1 agg input; later p2|t2 (2*NO==NH)
    float* t1 = ws + NH;       // [NH]  becomes h in place after agg1
    int* cnt     = (int*)(ws + 2 * NH);           // [N]
    int* fillc   = cnt + N_NODES;                 // [N]
    int* row_ptr = fillc + N_NODES;               // [N]
    int* bsums   = row_ptr + N_NODES;             // [256]
    int* csr     = bsums + 256;                   // [E]

    const size_t need = (2 * NH) * sizeof(float) +
                        (3 * (size_t)N_NODES + 256 + N_EDGES) * sizeof(int);
    if (ws_size < need) return;

    hipMemsetAsync(cnt, 0, 2 * N_NODES * sizeof(int), stream);  // cnt + fillc

    // CSR build (independent of mm1; same stream serializes correctly)
    hist_kernel<<<(N_EDGES + 255) / 256, 256, 0, stream>>>(dst, cnt);
    scan_reduce_kernel<<<NBLK, 256, 0, stream>>>(cnt, bsums);
    scan_bsums_kernel<<<1, 256, 0, stream>>>(bsums);
    scan_final_kernel<<<NBLK, 256, 0, stream>>>(cnt, bsums, row_ptr);
    fill_kernel<<<(N_EDGES + 255) / 256, 256, 0, stream>>>(src, dst, row_ptr, fillc, csr);

    // Layer 1
    mm1_kernel<<<(N_NODES + 7) / 8, 128, 0, stream>>>(x, W1l, W1r, p1, t1);
    agg1_kernel<<<N_NODES, 128, 0, stream>>>(p1, t1, b1, row_ptr, cnt, csr);
    float* h = t1;   // in-place

    // Layer 2 (pre-transform: agg(h)@W == agg(h@W); aggregates 64ch not 128)
    float* p2 = p1;
    float* t2 = p1 + NO;
    mm2_kernel<<<(N_NODES + 7) / 8, 128, 0, stream>>>(h, W2l, W2r, p2, t2);
    agg2_kernel<<<N_NODES, 64, 0, stream>>>(p2, t2, b2, row_ptr, cnt, csr, out);
}

// Round 3
// 267.702 us; speedup vs baseline: 2.8757x; 1.3596x over previous
//
#include <hip/hip_runtime.h>

#define N_NODES 50000
#define N_EDGES 800000
#define IN_C    128
#define HID_C   128
#define OUT_C   64
#define NBLK    ((N_NODES + 255) / 256)   // 196 scan blocks

typedef unsigned short ushort_t;
typedef unsigned int   uint_t;
typedef __attribute__((ext_vector_type(8))) short bf16x8;   // 8 bf16 in 4 VGPRs
typedef __attribute__((ext_vector_type(4))) float f32x4;

// fp32 -> bf16 (round-to-nearest-even), manual to avoid header overload surprises
__device__ inline ushort_t f2bf(float f) {
    uint_t u = __float_as_uint(f);
    uint_t r = (u + 0x7fffu + ((u >> 16) & 1u)) >> 16;
    return (ushort_t)r;
}

// ---------------------------------------------------------------------------
// Weight pre-pack into B-fragment order for mfma_f32_16x16x32_bf16:
//   packed[((ct*KT + kt)*64 + lane)*8 + j] = bf16( W[kt*32 + (lane>>4)*8 + j][ct*16 + (lane&15)] )
// so a wave's B-frag load is one coalesced 16B read per lane.
// ---------------------------------------------------------------------------
__device__ inline void pack_one(const float* W, ushort_t* Wp, int K, int N, int idx) {
    const int j  = idx & 7;
    const int L  = (idx >> 3) & 63;
    const int t  = idx >> 9;          // ct*KT + kt
    const int KT = K / 32;
    const int kt = t % KT;
    const int ct = t / KT;
    const int k  = kt * 32 + (L >> 4) * 8 + j;
    const int n  = ct * 16 + (L & 15);
    Wp[idx] = f2bf(W[k * N + n]);
}

__global__ __launch_bounds__(256) void pack_w_kernel(
    const float* __restrict__ W1l, const float* __restrict__ W1r,
    const float* __restrict__ W2l, const float* __restrict__ W2r,
    ushort_t* __restrict__ wpack)   // [16384 | 16384 | 8192 | 8192]
{
    const int tid = blockIdx.x * 256 + threadIdx.x;    // 192 blocks -> 49152 threads
    if (tid < 16384)              pack_one(W1l, wpack,          IN_C,  HID_C, tid);
    else if (tid < 32768)         pack_one(W1r, wpack + 16384,  IN_C,  HID_C, tid - 16384);
    else if (tid < 40960)         pack_one(W2l, wpack + 32768,  HID_C, OUT_C, tid - 32768);
    else if (tid < 49152)         pack_one(W2r, wpack + 40960,  HID_C, OUT_C, tid - 40960);
}

// ---------------------------------------------------------------------------
// CSR build: histogram of dst, exclusive scan, edge fill.
// ---------------------------------------------------------------------------
__global__ __launch_bounds__(256) void hist_kernel(
    const int* __restrict__ dst, int* cnt)
{
    const int e = blockIdx.x * 256 + threadIdx.x;
    if (e < N_EDGES) atomicAdd(&cnt[dst[e]], 1);
}

__global__ __launch_bounds__(256) void scan_reduce_kernel(
    const int* __restrict__ cnt, int* __restrict__ bsums)
{
    __shared__ int s[256];
    const int t = threadIdx.x;
    const int i = blockIdx.x * 256 + t;
    s[t] = (i < N_NODES) ? cnt[i] : 0;
    __syncthreads();
    for (int off = 128; off > 0; off >>= 1) {
        if (t < off) s[t] += s[t + off];
        __syncthreads();
    }
    if (t == 0) bsums[blockIdx.x] = s[0];
}

__global__ __launch_bounds__(256) void scan_bsums_kernel(int* bsums)
{
    __shared__ int s[256];
    const int t = threadIdx.x;
    const int v = (t < NBLK) ? bsums[t] : 0;
    s[t] = v;
    __syncthreads();
    for (int off = 1; off < 256; off <<= 1) {
        const int add = (t >= off) ? s[t - off] : 0;
        __syncthreads();
        s[t] += add;
        __syncthreads();
    }
    if (t < NBLK) bsums[t] = s[t] - v;   // exclusive
}

__global__ __launch_bounds__(256) void scan_final_kernel(
    const int* __restrict__ cnt, const int* __restrict__ bsums,
    int* __restrict__ row_ptr)
{
    __shared__ int s[256];
    const int t = threadIdx.x;
    const int i = blockIdx.x * 256 + t;
    const int v = (i < N_NODES) ? cnt[i] : 0;
    s[t] = v;
    __syncthreads();
    for (int off = 1; off < 256; off <<= 1) {
        const int add = (t >= off) ? s[t - off] : 0;
        __syncthreads();
        s[t] += add;
        __syncthreads();
    }
    if (i < N_NODES) row_ptr[i] = s[t] - v + bsums[blockIdx.x];
}

__global__ __launch_bounds__(256) void fill_kernel(
    const int* __restrict__ src, const int* __restrict__ dst,
    const int* __restrict__ row_ptr, int* fillc, int* __restrict__ csr)
{
    const int e = blockIdx.x * 256 + threadIdx.x;
    if (e < N_EDGES) {
        const int d = dst[e];
        const int pos = atomicAdd(&fillc[d], 1);
        csr[row_ptr[d] + pos] = src[e];
    }
}

// ---------------------------------------------------------------------------
// Layer-1 MFMA dual matmul: p1b = bf16(x @ W1l), t1 = x @ W1r (fp32).
// Block = 256 (4 waves); wave w owns a 16-row strip of a 64-row tile.
// A-frags read fp32 x directly + inline cvt; B-frags from packed weights.
// ---------------------------------------------------------------------------
__global__ __launch_bounds__(256) void mm1_mfma(
    const float* __restrict__ x,
    const ushort_t* __restrict__ wpack,
    ushort_t* __restrict__ p1b, float* __restrict__ t1)
{
    const int wave = threadIdx.x >> 6;
    const int lane = threadIdx.x & 63;
    const int quad = lane >> 4;
    const int m    = lane & 15;
    const int row0 = blockIdx.x * 64 + wave * 16;
    const int arow = min(row0 + m, N_NODES - 1);      // clamped A-load row

    const bf16x8* Bl = (const bf16x8*)(wpack);         // W1l packed: 8 ct x 4 kt
    const bf16x8* Br = (const bf16x8*)(wpack + 16384); // W1r packed

    f32x4 accl[8], accr[8];
#pragma unroll
    for (int ct = 0; ct < 8; ++ct) { accl[ct] = (f32x4)(0.0f); accr[ct] = (f32x4)(0.0f); }

#pragma unroll
    for (int kt = 0; kt < 4; ++kt) {
        const float* xp = x + (size_t)arow * IN_C + kt * 32 + quad * 8;
        const float4 a0 = *(const float4*)(xp);
        const float4 a1 = *(const float4*)(xp + 4);
        bf16x8 af;
        af[0] = (short)f2bf(a0.x); af[1] = (short)f2bf(a0.y);
        af[2] = (short)f2bf(a0.z); af[3] = (short)f2bf(a0.w);
        af[4] = (short)f2bf(a1.x); af[5] = (short)f2bf(a1.y);
        af[6] = (short)f2bf(a1.z); af[7] = (short)f2bf(a1.w);
#pragma unroll
        for (int ct = 0; ct < 8; ++ct) {
            const bf16x8 bl = Bl[(ct * 4 + kt) * 64 + lane];
            const bf16x8 br = Br[(ct * 4 + kt) * 64 + lane];
            accl[ct] = __builtin_amdgcn_mfma_f32_16x16x32_bf16(af, bl, accl[ct], 0, 0, 0);
            accr[ct] = __builtin_amdgcn_mfma_f32_16x16x32_bf16(af, br, accr[ct], 0, 0, 0);
        }
    }

    // D layout: col = lane&15, row = quad*4 + r
#pragma unroll
    for (int r = 0; r < 4; ++r) {
        const int orow = row0 + quad * 4 + r;
        if (orow < N_NODES) {
#pragma unroll
            for (int ct = 0; ct < 8; ++ct) {
                const int col = ct * 16 + m;
                p1b[(size_t)orow * HID_C + col] = f2bf(accl[ct][r]);
                t1 [(size_t)orow * HID_C + col] = accr[ct][r];
            }
        }
    }
}

// ---------------------------------------------------------------------------
// agg1: one node per 64-thread block; lane = channel pair (bf16x2 gathers).
// h = relu(mean(p1[src]) + b1 + t1), stored bf16 row-major for mm2.
// ---------------------------------------------------------------------------
__global__ __launch_bounds__(64) void agg1_kernel(
    const ushort_t* __restrict__ p1b, const float* __restrict__ t1,
    const float* __restrict__ b1, const int* __restrict__ row_ptr,
    const int* __restrict__ cnt, const int* __restrict__ csr,
    ushort_t* __restrict__ hb)
{
    const int node  = blockIdx.x;
    const int c2    = threadIdx.x;          // channel pair 0..63
    const int start = row_ptr[node];
    const int degi  = cnt[node];

    float ax = 0.0f, ay = 0.0f;
    int e = 0;
    for (; e + 1 < degi; e += 2) {
        const int s0 = csr[start + e];
        const int s1 = csr[start + e + 1];
        const uint_t v0 = *(const uint_t*)(p1b + (size_t)s0 * HID_C + c2 * 2);
        const uint_t v1 = *(const uint_t*)(p1b + (size_t)s1 * HID_C + c2 * 2);
        ax += __uint_as_float(v0 << 16) + __uint_as_float(v1 << 16);
        ay += __uint_as_float(v0 & 0xffff0000u) + __uint_as_float(v1 & 0xffff0000u);
    }
    if (e < degi) {
        const int s0 = csr[start + e];
        const uint_t v0 = *(const uint_t*)(p1b + (size_t)s0 * HID_C + c2 * 2);
        ax += __uint_as_float(v0 << 16);
        ay += __uint_as_float(v0 & 0xffff0000u);
    }

    const float inv = 1.0f / fmaxf((float)degi, 1.0f);
    const size_t i = (size_t)node * HID_C + c2 * 2;
    const float2 tv = *(const float2*)(t1 + i);
    const float2 bv = *(const float2*)(b1 + c2 * 2);
    const float h0 = fmaxf(fmaf(ax, inv, bv.x + tv.x), 0.0f);
    const float h1 = fmaxf(fmaf(ay, inv, bv.y + tv.y), 0.0f);
    *(uint_t*)(hb + i) = (uint_t)f2bf(h0) | ((uint_t)f2bf(h1) << 16);
}

// ---------------------------------------------------------------------------
// Layer-2 MFMA dual matmul: p2b = bf16(h @ W2l), t2 = h @ W2r (fp32).
// h already bf16 row-major -> direct 16B A-frag loads.
// ---------------------------------------------------------------------------
__global__ __launch_bounds__(256) void mm2_mfma(
    const ushort_t* __restrict__ hb,
    const ushort_t* __restrict__ wpack,
    ushort_t* __restrict__ p2b, float* __restrict__ t2)
{
    const int wave = threadIdx.x >> 6;
    const int lane = threadIdx.x & 63;
    const int quad = lane >> 4;
    const int m    = lane & 15;
    const int row0 = blockIdx.x * 64 + wave * 16;
    const int arow = min(row0 + m, N_NODES - 1);

    const bf16x8* Bl = (const bf16x8*)(wpack + 32768); // W2l packed: 4 ct x 4 kt
    const bf16x8* Br = (const bf16x8*)(wpack + 40960); // W2r packed

    f32x4 accl[4], accr[4];
#pragma unroll
    for (int ct = 0; ct < 4; ++ct) { accl[ct] = (f32x4)(0.0f); accr[ct] = (f32x4)(0.0f); }

#pragma unroll
    for (int kt = 0; kt < 4; ++kt) {
        const bf16x8 af = *(const bf16x8*)(hb + (size_t)arow * HID_C + kt * 32 + quad * 8);
#pragma unroll
        for (int ct = 0; ct < 4; ++ct) {
            const bf16x8 bl = Bl[(ct * 4 + kt) * 64 + lane];
            const bf16x8 br = Br[(ct * 4 + kt) * 64 + lane];
            accl[ct] = __builtin_amdgcn_mfma_f32_16x16x32_bf16(af, bl, accl[ct], 0, 0, 0);
            accr[ct] = __builtin_amdgcn_mfma_f32_16x16x32_bf16(af, br, accr[ct], 0, 0, 0);
        }
    }

#pragma unroll
    for (int r = 0; r < 4; ++r) {
        const int orow = row0 + quad * 4 + r;
        if (orow < N_NODES) {
#pragma unroll
            for (int ct = 0; ct < 4; ++ct) {
                const int col = ct * 16 + m;
                p2b[(size_t)orow * OUT_C + col] = f2bf(accl[ct][r]);
                t2 [(size_t)orow * OUT_C + col] = accr[ct][r];
            }
        }
    }
}

// ---------------------------------------------------------------------------
// agg2: one node per 64-thread block; lane = channel. out = mean(p2[src]) + b2 + t2.
// ---------------------------------------------------------------------------
__global__ __launch_bounds__(64) void agg2_kernel(
    const ushort_t* __restrict__ p2b, const float* __restrict__ t2,
    const float* __restrict__ b2, const int* __restrict__ row_ptr,
    const int* __restrict__ cnt, const int* __restrict__ csr,
    float* __restrict__ out)
{
    const int node  = blockIdx.x;
    const int c     = threadIdx.x;          // channel 0..63
    const int start = row_ptr[node];
    const int degi  = cnt[node];

    float acc = 0.0f;
    int e = 0;
    for (; e + 1 < degi; e += 2) {
        const int s0 = csr[start + e];
        const int s1 = csr[start + e + 1];
        const uint_t u0 = p2b[(size_t)s0 * OUT_C + c];
        const uint_t u1 = p2b[(size_t)s1 * OUT_C + c];
        acc += __uint_as_float(u0 << 16) + __uint_as_float(u1 << 16);
    }
    if (e < degi) {
        const uint_t u0 = p2b[(size_t)csr[start + e] * OUT_C + c];
        acc += __uint_as_float(u0 << 16);
    }

    const float inv = 1.0f / fmaxf((float)degi, 1.0f);
    const size_t i = (size_t)node * OUT_C + c;
    out[i] = fmaf(acc, inv, b2[c] + t2[i]);
}

extern "C" void kernel_launch(void* const* d_in, const int* in_sizes, int n_in,
                              void* d_out, int out_size, void* d_ws, size_t ws_size,
                              hipStream_t stream)
{
    const float* x   = (const float*)d_in[0];
    const int*   ei  = (const int*)d_in[1];
    const float* W1l = (const float*)d_in[2];
    const float* b1  = (const float*)d_in[3];
    const float* W1r = (const float*)d_in[4];
    const float* W2l = (const float*)d_in[5];
    const float* b2  = (const float*)d_in[6];
    const float* W2r = (const float*)d_in[7];
    float* out = (float*)d_out;

    const int* src = ei;
    const int* dst = ei + N_EDGES;

    const size_t NH = (size_t)N_NODES * HID_C;   // 6.4M
    const size_t NO = (size_t)N_NODES * OUT_C;   // 3.2M

    // Workspace layout (floats first, then ushorts, then ints; all 4B-aligned)
    char* ws = (char*)d_ws;
    float*    t1    = (float*)ws;                      ws += NH * sizeof(float);
    float*    t2    = (float*)ws;                      ws += NO * sizeof(float);
    ushort_t* p1b   = (ushort_t*)ws;                   ws += NH * sizeof(ushort_t);
    ushort_t* hb    = (ushort_t*)ws;                   ws += NH * sizeof(ushort_t);
    ushort_t* p2b   = (ushort_t*)ws;                   ws += NO * sizeof(ushort_t);
    ushort_t* wpack = (ushort_t*)ws;                   ws += 49152 * sizeof(ushort_t);
    int* cnt     = (int*)ws;                           ws += N_NODES * sizeof(int);
    int* fillc   = (int*)ws;                           ws += N_NODES * sizeof(int);
    int* row_ptr = (int*)ws;                           ws += N_NODES * sizeof(int);
    int* bsums   = (int*)ws;                           ws += 256 * sizeof(int);
    int* csr     = (int*)ws;                           ws += N_EDGES * sizeof(int);

    const size_t need = (size_t)(ws - (char*)d_ws);
    if (ws_size < need) return;

    hipMemsetAsync(cnt, 0, 2 * N_NODES * sizeof(int), stream);  // cnt + fillc

    // Weight pack + CSR build
    pack_w_kernel<<<192, 256, 0, stream>>>(W1l, W1r, W2l, W2r, wpack);
    hist_kernel<<<(N_EDGES + 255) / 256, 256, 0, stream>>>(dst, cnt);
    scan_reduce_kernel<<<NBLK, 256, 0, stream>>>(cnt, bsums);
    scan_bsums_kernel<<<1, 256, 0, stream>>>(bsums);
    scan_final_kernel<<<NBLK, 256, 0, stream>>>(cnt, bsums, row_ptr);
    fill_kernel<<<(N_EDGES + 255) / 256, 256, 0, stream>>>(src, dst, row_ptr, fillc, csr);

    // Layer 1
    mm1_mfma<<<(N_NODES + 63) / 64, 256, 0, stream>>>(x, wpack, p1b, t1);
    agg1_kernel<<<N_NODES, 64, 0, stream>>>(p1b, t1, b1, row_ptr, cnt, csr, hb);

    // Layer 2 (pre-transform: agg(h)@W == agg(h@W); aggregates 64ch bf16)
    mm2_mfma<<<(N_NODES + 63) / 64, 256, 0, stream>>>(hb, wpack, p2b, t2);
    agg2_kernel<<<N_NODES, 64, 0, stream>>>(p2b, t2, b2, row_ptr, cnt, csr, out);
}

// Round 4
// 217.749 us; speedup vs baseline: 3.5354x; 1.2294x over previous
//
#include <hip/hip_runtime.h>

#define N_NODES 50000
#define N_EDGES 800000
#define IN_C    128
#define HID_C   128
#define OUT_C   64
#define NBUCK   196                         // ceil(50000/256) buckets of 256 nodes
#define EPB     2048                        // edges per block in bucket kernels
#define EBLKS   ((N_EDGES + EPB - 1) / EPB) // 391

typedef unsigned short ushort_t;
typedef unsigned int   uint_t;
typedef __attribute__((ext_vector_type(8))) short bf16x8;
typedef __attribute__((ext_vector_type(4))) float f32x4;

__device__ inline ushort_t f2bf(float f) {
    uint_t u = __float_as_uint(f);
    uint_t r = (u + 0x7fffu + ((u >> 16) & 1u)) >> 16;
    return (ushort_t)r;
}

// ---------------------------------------------------------------------------
// Weight pre-pack into B-fragment order for mfma_f32_16x16x32_bf16.
// ---------------------------------------------------------------------------
__device__ inline void pack_one(const float* W, ushort_t* Wp, int K, int N, int idx) {
    const int j  = idx & 7;
    const int L  = (idx >> 3) & 63;
    const int t  = idx >> 9;
    const int KT = K / 32;
    const int kt = t % KT;
    const int ct = t / KT;
    const int k  = kt * 32 + (L >> 4) * 8 + j;
    const int n  = ct * 16 + (L & 15);
    Wp[idx] = f2bf(W[k * N + n]);
}

__global__ __launch_bounds__(256) void pack_w_kernel(
    const float* __restrict__ W1l, const float* __restrict__ W1r,
    const float* __restrict__ W2l, const float* __restrict__ W2r,
    ushort_t* __restrict__ wpack)
{
    const int tid = blockIdx.x * 256 + threadIdx.x;
    if (tid < 16384)              pack_one(W1l, wpack,          IN_C,  HID_C, tid);
    else if (tid < 32768)         pack_one(W1r, wpack + 16384,  IN_C,  HID_C, tid - 16384);
    else if (tid < 40960)         pack_one(W2l, wpack + 32768,  HID_C, OUT_C, tid - 32768);
    else if (tid < 49152)         pack_one(W2r, wpack + 40960,  HID_C, OUT_C, tid - 40960);
}

// ---------------------------------------------------------------------------
// CSR build, two-level counting sort by dst bucket (bucket = dst>>8).
// ---------------------------------------------------------------------------
__global__ __launch_bounds__(256) void bucket_count_kernel(
    const int* __restrict__ dst, int* bcnt)
{
    __shared__ int lh[NBUCK];
    for (int i = threadIdx.x; i < NBUCK; i += 256) lh[i] = 0;
    __syncthreads();
    const int base = blockIdx.x * EPB;
    for (int i = threadIdx.x; i < EPB; i += 256) {
        const int e = base + i;
        if (e < N_EDGES) atomicAdd(&lh[dst[e] >> 8], 1);
    }
    __syncthreads();
    for (int i = threadIdx.x; i < NBUCK; i += 256) {
        const int v = lh[i];
        if (v) atomicAdd(&bcnt[i], v);
    }
}

__global__ __launch_bounds__(256) void bucket_scan_kernel(
    const int* __restrict__ bcnt, int* __restrict__ ebase, int* __restrict__ gcur)
{
    __shared__ int s[256];
    const int t = threadIdx.x;
    const int v = (t < NBUCK) ? bcnt[t] : 0;
    s[t] = v;
    __syncthreads();
    for (int off = 1; off < 256; off <<= 1) {
        const int add = (t >= off) ? s[t - off] : 0;
        __syncthreads();
        s[t] += add;
        __syncthreads();
    }
    if (t < NBUCK) { const int ex = s[t] - v; ebase[t] = ex; gcur[t] = ex; }
    if (t == NBUCK - 1) ebase[NBUCK] = s[t];
}

// Each block claims one contiguous run per bucket -> lines owned by one block.
__global__ __launch_bounds__(256) void bucket_scatter_kernel(
    const int* __restrict__ src, const int* __restrict__ dst,
    int* gcur, int2* __restrict__ ebuf)
{
    __shared__ int lh[256], gbase[256], lcur[256];
    const int t = threadIdx.x;
    lh[t] = 0;
    __syncthreads();
    const int base = blockIdx.x * EPB;
    int s8[8], d8[8], b8[8];
#pragma unroll
    for (int j = 0; j < 8; ++j) {
        const int e = base + t + j * 256;
        if (e < N_EDGES) {
            s8[j] = src[e]; d8[j] = dst[e]; b8[j] = d8[j] >> 8;
            atomicAdd(&lh[b8[j]], 1);
        } else b8[j] = -1;
    }
    __syncthreads();
    if (t < NBUCK) {
        const int run = lh[t];
        if (run > 0) gbase[t] = atomicAdd(&gcur[t], run);
        lcur[t] = 0;
    }
    __syncthreads();
#pragma unroll
    for (int j = 0; j < 8; ++j) {
        const int b = b8[j];
        if (b >= 0) {
            const int p = atomicAdd(&lcur[b], 1);
            ebuf[gbase[b] + p] = make_int2(s8[j], d8[j]);
        }
    }
}

// One block per bucket: local hist+scan over 256 nodes; writes cnt, row_ptr,
// and csr confined to the bucket's exclusive range.
__global__ __launch_bounds__(256) void bucket_fill_kernel(
    const int2* __restrict__ ebuf, const int* __restrict__ ebase,
    int* __restrict__ cnt, int* __restrict__ row_ptr, int* __restrict__ csr)
{
    __shared__ int lh[256], loff[256], lcur[256];
    const int b = blockIdx.x;
    const int t = threadIdx.x;
    const int e0 = ebase[b];
    const int nb = ebase[b + 1] - e0;
    lh[t] = 0;
    __syncthreads();
    for (int i = t; i < nb; i += 256) atomicAdd(&lh[ebuf[e0 + i].y & 255], 1);
    __syncthreads();
    const int v = lh[t];
    loff[t] = v;
    __syncthreads();
    for (int off = 1; off < 256; off <<= 1) {
        const int add = (t >= off) ? loff[t - off] : 0;
        __syncthreads();
        loff[t] += add;
        __syncthreads();
    }
    const int ex = loff[t] - v;
    const int node = b * 256 + t;
    if (node < N_NODES) { cnt[node] = v; row_ptr[node] = e0 + ex; }
    lcur[t] = ex;
    __syncthreads();
    for (int i = t; i < nb; i += 256) {
        const int2 pr = ebuf[e0 + i];
        const int p = atomicAdd(&lcur[pr.y & 255], 1);
        csr[e0 + p] = pr.x;
    }
}

// ---------------------------------------------------------------------------
// Layer-1 MFMA dual matmul: p1b = bf16(x @ W1l), t1 = x @ W1r (fp32).
// ---------------------------------------------------------------------------
__global__ __launch_bounds__(256) void mm1_mfma(
    const float* __restrict__ x,
    const ushort_t* __restrict__ wpack,
    ushort_t* __restrict__ p1b, float* __restrict__ t1)
{
    const int wave = threadIdx.x >> 6;
    const int lane = threadIdx.x & 63;
    const int quad = lane >> 4;
    const int m    = lane & 15;
    const int row0 = blockIdx.x * 64 + wave * 16;
    const int arow = min(row0 + m, N_NODES - 1);

    const bf16x8* Bl = (const bf16x8*)(wpack);
    const bf16x8* Br = (const bf16x8*)(wpack + 16384);

    f32x4 accl[8], accr[8];
#pragma unroll
    for (int ct = 0; ct < 8; ++ct) { accl[ct] = (f32x4)(0.0f); accr[ct] = (f32x4)(0.0f); }

#pragma unroll
    for (int kt = 0; kt < 4; ++kt) {
        const float* xp = x + (size_t)arow * IN_C + kt * 32 + quad * 8;
        const float4 a0 = *(const float4*)(xp);
        const float4 a1 = *(const float4*)(xp + 4);
        bf16x8 af;
        af[0] = (short)f2bf(a0.x); af[1] = (short)f2bf(a0.y);
        af[2] = (short)f2bf(a0.z); af[3] = (short)f2bf(a0.w);
        af[4] = (short)f2bf(a1.x); af[5] = (short)f2bf(a1.y);
        af[6] = (short)f2bf(a1.z); af[7] = (short)f2bf(a1.w);
#pragma unroll
        for (int ct = 0; ct < 8; ++ct) {
            const bf16x8 bl = Bl[(ct * 4 + kt) * 64 + lane];
            const bf16x8 br = Br[(ct * 4 + kt) * 64 + lane];
            accl[ct] = __builtin_amdgcn_mfma_f32_16x16x32_bf16(af, bl, accl[ct], 0, 0, 0);
            accr[ct] = __builtin_amdgcn_mfma_f32_16x16x32_bf16(af, br, accr[ct], 0, 0, 0);
        }
    }

#pragma unroll
    for (int r = 0; r < 4; ++r) {
        const int orow = row0 + quad * 4 + r;
        if (orow < N_NODES) {
#pragma unroll
            for (int ct = 0; ct < 8; ++ct) {
                const int col = ct * 16 + m;
                p1b[(size_t)orow * HID_C + col] = f2bf(accl[ct][r]);
                t1 [(size_t)orow * HID_C + col] = accr[ct][r];
            }
        }
    }
}

// ---------------------------------------------------------------------------
// agg1: one node per 64-thread block; lane = channel pair. Unroll-4 gathers.
// ---------------------------------------------------------------------------
__global__ __launch_bounds__(64) void agg1_kernel(
    const ushort_t* __restrict__ p1b, const float* __restrict__ t1,
    const float* __restrict__ b1, const int* __restrict__ row_ptr,
    const int* __restrict__ cnt, const int* __restrict__ csr,
    ushort_t* __restrict__ hb)
{
    const int node  = blockIdx.x;
    const int c2    = threadIdx.x;
    const int start = row_ptr[node];
    const int degi  = cnt[node];

    float ax = 0.0f, ay = 0.0f;
    int e = 0;
    for (; e + 3 < degi; e += 4) {
        const int s0 = csr[start + e];
        const int s1 = csr[start + e + 1];
        const int s2 = csr[start + e + 2];
        const int s3 = csr[start + e + 3];
        const uint_t v0 = *(const uint_t*)(p1b + (size_t)s0 * HID_C + c2 * 2);
        const uint_t v1 = *(const uint_t*)(p1b + (size_t)s1 * HID_C + c2 * 2);
        const uint_t v2 = *(const uint_t*)(p1b + (size_t)s2 * HID_C + c2 * 2);
        const uint_t v3 = *(const uint_t*)(p1b + (size_t)s3 * HID_C + c2 * 2);
        ax += __uint_as_float(v0 << 16) + __uint_as_float(v1 << 16)
            + __uint_as_float(v2 << 16) + __uint_as_float(v3 << 16);
        ay += __uint_as_float(v0 & 0xffff0000u) + __uint_as_float(v1 & 0xffff0000u)
            + __uint_as_float(v2 & 0xffff0000u) + __uint_as_float(v3 & 0xffff0000u);
    }
    for (; e < degi; ++e) {
        const int s0 = csr[start + e];
        const uint_t v0 = *(const uint_t*)(p1b + (size_t)s0 * HID_C + c2 * 2);
        ax += __uint_as_float(v0 << 16);
        ay += __uint_as_float(v0 & 0xffff0000u);
    }

    const float inv = 1.0f / fmaxf((float)degi, 1.0f);
    const size_t i = (size_t)node * HID_C + c2 * 2;
    const float2 tv = *(const float2*)(t1 + i);
    const float2 bv = *(const float2*)(b1 + c2 * 2);
    const float h0 = fmaxf(fmaf(ax, inv, bv.x + tv.x), 0.0f);
    const float h1 = fmaxf(fmaf(ay, inv, bv.y + tv.y), 0.0f);
    *(uint_t*)(hb + i) = (uint_t)f2bf(h0) | ((uint_t)f2bf(h1) << 16);
}

// ---------------------------------------------------------------------------
// Layer-2 MFMA dual matmul: p2b = bf16(h @ W2l), t2 = h @ W2r (fp32).
// ---------------------------------------------------------------------------
__global__ __launch_bounds__(256) void mm2_mfma(
    const ushort_t* __restrict__ hb,
    const ushort_t* __restrict__ wpack,
    ushort_t* __restrict__ p2b, float* __restrict__ t2)
{
    const int wave = threadIdx.x >> 6;
    const int lane = threadIdx.x & 63;
    const int quad = lane >> 4;
    const int m    = lane & 15;
    const int row0 = blockIdx.x * 64 + wave * 16;
    const int arow = min(row0 + m, N_NODES - 1);

    const bf16x8* Bl = (const bf16x8*)(wpack + 32768);
    const bf16x8* Br = (const bf16x8*)(wpack + 40960);

    f32x4 accl[4], accr[4];
#pragma unroll
    for (int ct = 0; ct < 4; ++ct) { accl[ct] = (f32x4)(0.0f); accr[ct] = (f32x4)(0.0f); }

#pragma unroll
    for (int kt = 0; kt < 4; ++kt) {
        const bf16x8 af = *(const bf16x8*)(hb + (size_t)arow * HID_C + kt * 32 + quad * 8);
#pragma unroll
        for (int ct = 0; ct < 4; ++ct) {
            const bf16x8 bl = Bl[(ct * 4 + kt) * 64 + lane];
            const bf16x8 br = Br[(ct * 4 + kt) * 64 + lane];
            accl[ct] = __builtin_amdgcn_mfma_f32_16x16x32_bf16(af, bl, accl[ct], 0, 0, 0);
            accr[ct] = __builtin_amdgcn_mfma_f32_16x16x32_bf16(af, br, accr[ct], 0, 0, 0);
        }
    }

#pragma unroll
    for (int r = 0; r < 4; ++r) {
        const int orow = row0 + quad * 4 + r;
        if (orow < N_NODES) {
#pragma unroll
            for (int ct = 0; ct < 4; ++ct) {
                const int col = ct * 16 + m;
                p2b[(size_t)orow * OUT_C + col] = f2bf(accl[ct][r]);
                t2 [(size_t)orow * OUT_C + col] = accr[ct][r];
            }
        }
    }
}

// ---------------------------------------------------------------------------
// agg2: one node per 64-thread block; lane = channel. Unroll-4 gathers.
// ---------------------------------------------------------------------------
__global__ __launch_bounds__(64) void agg2_kernel(
    const ushort_t* __restrict__ p2b, const float* __restrict__ t2,
    const float* __restrict__ b2, const int* __restrict__ row_ptr,
    const int* __restrict__ cnt, const int* __restrict__ csr,
    float* __restrict__ out)
{
    const int node  = blockIdx.x;
    const int c     = threadIdx.x;
    const int start = row_ptr[node];
    const int degi  = cnt[node];

    float acc = 0.0f;
    int e = 0;
    for (; e + 3 < degi; e += 4) {
        const int s0 = csr[start + e];
        const int s1 = csr[start + e + 1];
        const int s2 = csr[start + e + 2];
        const int s3 = csr[start + e + 3];
        const uint_t u0 = p2b[(size_t)s0 * OUT_C + c];
        const uint_t u1 = p2b[(size_t)s1 * OUT_C + c];
        const uint_t u2 = p2b[(size_t)s2 * OUT_C + c];
        const uint_t u3 = p2b[(size_t)s3 * OUT_C + c];
        acc += __uint_as_float(u0 << 16) + __uint_as_float(u1 << 16)
             + __uint_as_float(u2 << 16) + __uint_as_float(u3 << 16);
    }
    for (; e < degi; ++e) {
        const uint_t u0 = p2b[(size_t)csr[start + e] * OUT_C + c];
        acc += __uint_as_float(u0 << 16);
    }

    const float inv = 1.0f / fmaxf((float)degi, 1.0f);
    const size_t i = (size_t)node * OUT_C + c;
    out[i] = fmaf(acc, inv, b2[c] + t2[i]);
}

extern "C" void kernel_launch(void* const* d_in, const int* in_sizes, int n_in,
                              void* d_out, int out_size, void* d_ws, size_t ws_size,
                              hipStream_t stream)
{
    const float* x   = (const float*)d_in[0];
    const int*   ei  = (const int*)d_in[1];
    const float* W1l = (const float*)d_in[2];
    const float* b1  = (const float*)d_in[3];
    const float* W1r = (const float*)d_in[4];
    const float* W2l = (const float*)d_in[5];
    const float* b2  = (const float*)d_in[6];
    const float* W2r = (const float*)d_in[7];
    float* out = (float*)d_out;

    const int* src = ei;
    const int* dst = ei + N_EDGES;

    const size_t NH = (size_t)N_NODES * HID_C;   // 6.4M
    const size_t NO = (size_t)N_NODES * OUT_C;   // 3.2M

    // Workspace layout. ebuf (6.4 MB) aliases t1's region: ebuf is dead
    // before mm1 writes t1 (CSR build completes first).
    char* ws = (char*)d_ws;
    float*    t1    = (float*)ws;                      ws += NH * sizeof(float);
    float*    t2    = (float*)ws;                      ws += NO * sizeof(float);
    ushort_t* p1b   = (ushort_t*)ws;                   ws += NH * sizeof(ushort_t);
    ushort_t* hb    = (ushort_t*)ws;                   ws += NH * sizeof(ushort_t);
    ushort_t* p2b   = (ushort_t*)ws;                   ws += NO * sizeof(ushort_t);
    ushort_t* wpack = (ushort_t*)ws;                   ws += 49152 * sizeof(ushort_t);
    int* cnt     = (int*)ws;                           ws += N_NODES * sizeof(int);
    int* row_ptr = (int*)ws;                           ws += N_NODES * sizeof(int);
    int* csr     = (int*)ws;                           ws += N_EDGES * sizeof(int);
    int* bcnt    = (int*)ws;                           ws += NBUCK * sizeof(int);
    int* ebase   = (int*)ws;                           ws += (NBUCK + 1) * sizeof(int);
    int* gcur    = (int*)ws;                           ws += NBUCK * sizeof(int);
    int2* ebuf   = (int2*)t1;                          // aliased

    const size_t need = (size_t)(ws - (char*)d_ws);
    if (ws_size < need) return;

    hipMemsetAsync(bcnt, 0, NBUCK * sizeof(int), stream);

    // Weight pack + bucketed CSR build
    pack_w_kernel<<<192, 256, 0, stream>>>(W1l, W1r, W2l, W2r, wpack);
    bucket_count_kernel<<<EBLKS, 256, 0, stream>>>(dst, bcnt);
    bucket_scan_kernel<<<1, 256, 0, stream>>>(bcnt, ebase, gcur);
    bucket_scatter_kernel<<<EBLKS, 256, 0, stream>>>(src, dst, gcur, ebuf);
    bucket_fill_kernel<<<NBUCK, 256, 0, stream>>>(ebuf, ebase, cnt, row_ptr, csr);

    // Layer 1
    mm1_mfma<<<(N_NODES + 63) / 64, 256, 0, stream>>>(x, wpack, p1b, t1);
    agg1_kernel<<<N_NODES, 64, 0, stream>>>(p1b, t1, b1, row_ptr, cnt, csr, hb);

    // Layer 2
    mm2_mfma<<<(N_NODES + 63) / 64, 256, 0, stream>>>(hb, wpack, p2b, t2);
    agg2_kernel<<<N_NODES, 64, 0, stream>>>(p2b, t2, b2, row_ptr, cnt, csr, out);
}